// Round 10
// baseline (16328.979 us; speedup 1.0000x reference)
//
#include <hip/hip_runtime.h>

#define BB 32
#define TT 150
#define LL 400
#define FEATD 512
#define RNND 512
#define ATTD 512
#define EMBD 256
#define VOCABD 5000
#define G3 1536
#define LS3 16   // K3 l-chunks (25 l each)

__device__ __forceinline__ float fsigmoid(float x) { return 1.f / (1.f + __expf(-x)); }
__device__ __forceinline__ float ftanh(float x) {
    x = fminf(15.f, fmaxf(-15.f, x));
    float e = __expf(2.f * x);
    return 1.f - 2.f / (e + 1.f);
}
__device__ __forceinline__ void fma4(float4& a, const float4 w, const float s) {
    a.x += w.x * s; a.y += w.y * s; a.z += w.z * s; a.w += w.w * s;
}
// agent-scope (cross-XCD coherent) load: used ONLY by the K3 ticket-winner to
// read other blocks' atomicAdd results without relying on (non-coherent) L2.
__device__ __forceinline__ float gld(const float* p) {
    return __hip_atomic_load(p, __ATOMIC_RELAXED, __HIP_MEMORY_SCOPE_AGENT);
}

// ---------------- one-time GEMM: [B*L,512] @ [512,512] (fp and G) ----------------
__global__ void __launch_bounds__(256) k_proj512(const float* __restrict__ features,
                                                 const float* __restrict__ W,
                                                 float* __restrict__ outb) {
    __shared__ float sa[64 * 68];
    int blt = blockIdx.x >> 2, at = blockIdx.x & 3;
    int bl0 = blt * 64;
    int tid = threadIdx.x;
    int aq = tid & 31, blg = tid >> 5;
    float4 acc[8] = {};
    for (int kc = 0; kc < FEATD; kc += 64) {
        __syncthreads();
        for (int it = 0; it < 16; ++it) {
            int lin = it * 256 + tid;
            int k = lin & 63, bl = lin >> 6;
            sa[k * 68 + bl] = features[((size_t)bl0 + bl) * FEATD + kc + k];
        }
        __syncthreads();
#pragma unroll 4
        for (int k = 0; k < 64; ++k) {
            float4 w = *(const float4*)&W[(size_t)(kc + k) * 512 + at * 128 + aq * 4];
            float4 s0 = *(const float4*)&sa[k * 68 + blg * 8];
            float4 s1 = *(const float4*)&sa[k * 68 + blg * 8 + 4];
            fma4(acc[0], w, s0.x); fma4(acc[1], w, s0.y);
            fma4(acc[2], w, s0.z); fma4(acc[3], w, s0.w);
            fma4(acc[4], w, s1.x); fma4(acc[5], w, s1.y);
            fma4(acc[6], w, s1.z); fma4(acc[7], w, s1.w);
        }
    }
#pragma unroll
    for (int i = 0; i < 8; ++i)
        *(float4*)&outb[((size_t)bl0 + blg * 8 + i) * 512 + at * 128 + aq * 4] = acc[i];
}

// ---------------- K1: gate GEMM partials. 120 blocks ----------------
// mx: [emb(tok) | lo(t-1)] (K=768) @ Wk -> mxp[3], mh: h(t-1) @ Wr -> mhp[2].
// lo(t-1) is read directly from los slot t (materialized by K3's ticket winner).
__global__ void __launch_bounds__(256) k_gates(
    const float* __restrict__ emb, const int* __restrict__ formula,
    const float* __restrict__ Wk, const float* __restrict__ Wr,
    const float* __restrict__ hin, const float* __restrict__ lo,
    float* __restrict__ mxp, float* __restrict__ mhp, int t) {
    __shared__ float sm[256 * 36];
    __shared__ int stok[BB];
    int id = blockIdx.x, tid = threadIdx.x;
    bool isMX = id < 72;
    int jt, ks; const float* W; float* ob;
    if (isMX) { jt = id / 3; ks = id % 3; W = Wk; ob = mxp; }
    else { int r = id - 72; jt = r >> 1; ks = r & 1; W = Wr; ob = mhp; }
    int k0 = ks * 256;
    if (isMX && ks == 0 && tid < BB) stok[tid] = formula[tid * TT + t];
    __syncthreads();
    for (int it = 0; it < 32; ++it) {
        int lin = it * 256 + tid;
        int k = lin & 255, b = lin >> 8;
        float v;
        if (!isMX) v = hin[(size_t)b * RNND + k0 + k];
        else if (ks == 0) v = emb[(size_t)stok[b] * EMBD + k];
        else v = lo[(size_t)b * RNND + (ks - 1) * 256 + k];
        sm[k * 36 + b] = v;
    }
    __syncthreads();
    int jq = tid & 15, bg = tid >> 4;
    int j = jt * 64 + jq * 4;
    float4 a0 = {0, 0, 0, 0}, a1 = {0, 0, 0, 0};
#pragma unroll 4
    for (int k = 0; k < 256; ++k) {
        float4 w = *(const float4*)&W[(size_t)(k0 + k) * G3 + j];
        float2 s = *(const float2*)&sm[k * 36 + bg * 2];
        fma4(a0, w, s.x);
        fma4(a1, w, s.y);
    }
    int b = bg * 2;
    *(float4*)&ob[((size_t)ks * BB + b) * G3 + j] = a0;
    *(float4*)&ob[((size_t)ks * BB + b + 1) * G3 + j] = a1;
}

// ---------------- K2: combine -> h(t) + q|hpart partials; zero gdot/esum ----------------
// 128 blocks = tile(16) x ks(8, 64-k slices). Weights read exactly once/step.
// Also zeroes gdot/esum for K3's atomics (safe: K1 no longer reads them).
__global__ void __launch_bounds__(256) k_qh(
    const float* __restrict__ mxp, const float* __restrict__ mhp,
    const float* __restrict__ gruB, const float* __restrict__ W2,
    const float* __restrict__ outW, const float* __restrict__ hin,
    float* __restrict__ hout, float* __restrict__ qhp,
    float* __restrict__ gdot, float* __restrict__ esum) {
    __shared__ float sm[64 * 34];
    int bid = blockIdx.x, tid = threadIdx.x;
    int tile = bid >> 3, ks = bid & 7;
    if (bid < 8) {
        for (int i = tid; i < 2048; i += 256) gdot[bid * 2048 + i] = 0.f;
        if (bid == 0 && tid < BB) esum[tid] = 0.f;
    }
    int k0 = ks * 64;
    for (int it = 0; it < 8; ++it) {
        int lin = it * 256 + tid;
        int k = lin & 63, b = lin >> 6;
        int j = k0 + k;
        size_t m0 = ((size_t)0 * BB + b) * G3, m1 = ((size_t)1 * BB + b) * G3,
               m2 = ((size_t)2 * BB + b) * G3;
        float xz = gruB[j] + mxp[m0 + j] + mxp[m1 + j] + mxp[m2 + j];
        float xr = gruB[512 + j] + mxp[m0 + 512 + j] + mxp[m1 + 512 + j] + mxp[m2 + 512 + j];
        float xh = gruB[1024 + j] + mxp[m0 + 1024 + j] + mxp[m1 + 1024 + j] + mxp[m2 + 1024 + j];
        float rz = gruB[G3 + j] + mhp[m0 + j] + mhp[m1 + j];
        float rr = gruB[G3 + 512 + j] + mhp[m0 + 512 + j] + mhp[m1 + 512 + j];
        float rh = gruB[G3 + 1024 + j] + mhp[m0 + 1024 + j] + mhp[m1 + 1024 + j];
        float z = fsigmoid(xz + rz), r = fsigmoid(xr + rr);
        float hh = ftanh(xh + r * rh);
        float hn = z * hin[(size_t)b * RNND + j] + (1.f - z) * hh;
        sm[k * 34 + b] = hn;
        if (tile == 0) hout[(size_t)b * RNND + j] = hn;
    }
    __syncthreads();
    const float* W = (tile < 8) ? W2 : outW;  // outW rows [0,512) = h part
    int cb = (tile & 7) * 64;
    int jq = tid & 15, bg = tid >> 4;
    int j = cb + jq * 4;
    float4 a0 = {0, 0, 0, 0}, a1 = {0, 0, 0, 0};
#pragma unroll 4
    for (int k = 0; k < 64; ++k) {
        float4 w = *(const float4*)&W[(size_t)(k0 + k) * 512 + j];
        float2 s = *(const float2*)&sm[k * 34 + bg * 2];
        fma4(a0, w, s.x);
        fma4(a1, w, s.y);
    }
    int b = bg * 2;
    int outcol = tile * 64 + jq * 4;  // 0..1023
    *(float4*)&qhp[((size_t)ks * BB + b) * 1024 + outcol] = a0;
    *(float4*)&qhp[((size_t)ks * BB + b + 1) * 1024 + outcol] = a1;
}

// ---------------- K3: scores + exp + gdot atomics + last-block lo. 512 blocks = b x ls(16) ----------------
__global__ void __launch_bounds__(256) k_attn(
    const float* __restrict__ qhp, const float* __restrict__ V,
    const float* __restrict__ fp, const float* __restrict__ G,
    float* __restrict__ gdot, float* __restrict__ esum,
    unsigned* __restrict__ tick, float* __restrict__ lo_out) {
    __shared__ float sq[ATTD];
    __shared__ float sV[ATTD];
    __shared__ float se[32];
    __shared__ int swin;
    __shared__ float sES;
    int b = blockIdx.x >> 4, ls = blockIdx.x & 15, l0 = ls * 25;
    int tid = threadIdx.x;
    for (int c = tid; c < ATTD; c += 256) {
        float q = 0.f;
#pragma unroll
        for (int p = 0; p < 8; ++p) q += qhp[((size_t)p * BB + b) * 1024 + c];
        sq[c] = q;
        sV[c] = V[c];
    }
    __syncthreads();
    int lane = tid & 63, wv = tid >> 6;
    float4 q0 = ((const float4*)sq)[lane], q1 = ((const float4*)sq)[64 + lane];
    float4 v0 = ((const float4*)sV)[lane], v1 = ((const float4*)sV)[64 + lane];
    for (int ll = wv; ll < 25; ll += 4) {
        const float4* row = (const float4*)(fp + ((size_t)b * LL + l0 + ll) * ATTD);
        float4 f0 = row[lane], f1 = row[64 + lane];
        float d = ftanh(f0.x + q0.x) * v0.x + ftanh(f0.y + q0.y) * v0.y +
                  ftanh(f0.z + q0.z) * v0.z + ftanh(f0.w + q0.w) * v0.w +
                  ftanh(f1.x + q1.x) * v1.x + ftanh(f1.y + q1.y) * v1.y +
                  ftanh(f1.z + q1.z) * v1.z + ftanh(f1.w + q1.w) * v1.w;
#pragma unroll
        for (int o = 32; o > 0; o >>= 1) d += __shfl_xor(d, o);
        if (lane == 0) se[ll] = __expf(d);  // |score| <= sum|V| ~ 20, fp32-safe
    }
    __syncthreads();
    if (tid < 32) {
        float x = (tid < 25) ? se[tid] : 0.f;
#pragma unroll
        for (int o = 16; o > 0; o >>= 1) x += __shfl_xor(x, o);
        if (tid == 0) atomicAdd(&esum[b], x);
    }
    // gdot partial over this l-chunk (atomic accumulate; order jitter ~1e-7)
    {
        float a0 = 0.f, a1 = 0.f;
#pragma unroll 5
        for (int l = 0; l < 25; ++l) {
            float e = se[l];
            const float* gr = G + ((size_t)b * LL + l0 + l) * RNND;
            a0 += e * gr[tid];
            a1 += e * gr[tid + 256];
        }
        atomicAdd(&gdot[(size_t)b * RNND + tid], a0);
        atomicAdd(&gdot[(size_t)b * RNND + tid + 256], a1);
    }
    // last block for this b materializes lo(t) = tanh(hpart + gdot/esum)
    __threadfence();
    __syncthreads();
    if (tid == 0) swin = (atomicAdd(&tick[b], 1u) == LS3 - 1) ? 1 : 0;
    __syncthreads();
    if (swin) {
        if (tid == 0) sES = gld(&esum[b]);
        __syncthreads();
        float inv = 1.f / sES;
        for (int c = tid; c < RNND; c += 256) {
            float g = gld(&gdot[(size_t)b * RNND + c]);
            float hp = 0.f;
#pragma unroll
            for (int p = 0; p < 8; ++p)
                hp += qhp[((size_t)p * BB + b) * 1024 + 512 + c];
            lo_out[(size_t)b * RNND + c] = ftanh(hp + inv * g);
        }
        if (tid == 0)
            __hip_atomic_store(&tick[b], 0u, __ATOMIC_RELAXED,
                               __HIP_MEMORY_SCOPE_AGENT);
    }
}

// ---------------- final: logits = los[1..150] @ projW ----------------
// row r = b*150+t -> los slot t+1. 75 row-tiles x 40 v-tiles.
__global__ void __launch_bounds__(256) k_final(
    const float* __restrict__ los, const float* __restrict__ Wp,
    float* __restrict__ out) {
    __shared__ float sa[64 * 68];
    __shared__ unsigned srow[64];
    int mt = blockIdx.x / 40, vt = blockIdx.x % 40;
    int r0 = mt * 64;
    int tid = threadIdx.x;
    if (tid < 64) {
        int r = r0 + tid;
        int bb = r / TT, t = r % TT;
        srow[tid] = (unsigned)(((size_t)(t + 1) * BB + bb) * RNND);
    }
    int aq = tid & 31, blg = tid >> 5;
    int v = vt * 128 + aq * 4;
    bool vok = v < VOCABD;
    float4 acc[8] = {};
    __syncthreads();
    for (int kc = 0; kc < RNND; kc += 64) {
        for (int it = 0; it < 16; ++it) {
            int lin = it * 256 + tid;
            int k = lin & 63, rl = lin >> 6;
            sa[k * 68 + rl] = los[srow[rl] + kc + k];
        }
        __syncthreads();
        if (vok) {
#pragma unroll 4
            for (int k = 0; k < 64; ++k) {
                float4 w = *(const float4*)&Wp[(size_t)(kc + k) * VOCABD + v];
                float4 s0 = *(const float4*)&sa[k * 68 + blg * 8];
                float4 s1 = *(const float4*)&sa[k * 68 + blg * 8 + 4];
                fma4(acc[0], w, s0.x); fma4(acc[1], w, s0.y);
                fma4(acc[2], w, s0.z); fma4(acc[3], w, s0.w);
                fma4(acc[4], w, s1.x); fma4(acc[5], w, s1.y);
                fma4(acc[6], w, s1.z); fma4(acc[7], w, s1.w);
            }
        }
        __syncthreads();
    }
    if (vok) {
#pragma unroll
        for (int i = 0; i < 8; ++i)
            *(float4*)&out[(size_t)(r0 + blg * 8 + i) * VOCABD + v] = acc[i];
    }
}

extern "C" void kernel_launch(void* const* d_in, const int* in_sizes, int n_in,
                              void* d_out, int out_size, void* d_ws, size_t ws_size,
                              hipStream_t stream) {
    const float* features  = (const float*)d_in[0];
    const float* initstate = (const float*)d_in[1];
    const float* emb       = (const float*)d_in[2];
    const float* gruK      = (const float*)d_in[3];
    const float* gruR      = (const float*)d_in[4];
    const float* gruB      = (const float*)d_in[5];
    const float* W1        = (const float*)d_in[6];
    const float* W2        = (const float*)d_in[7];
    const float* V         = (const float*)d_in[8];
    const float* outW      = (const float*)d_in[9];
    const float* projW     = (const float*)d_in[10];
    const int*   formula   = (const int*)d_in[11];
    float* logits = (float*)d_out;

    float* ws = (float*)d_ws;
    float* h0    = ws;                                  // 16,384
    float* h1    = h0 + (size_t)BB * RNND;              // 16,384
    float* mxp   = h1 + (size_t)BB * RNND;              // 147,456
    float* mhp   = mxp + (size_t)3 * BB * G3;           // 98,304
    float* qhp   = mhp + (size_t)2 * BB * G3;           // 262,144
    float* gdot  = qhp + (size_t)8 * BB * 1024;         // 16,384
    float* esum  = gdot + (size_t)BB * RNND;            // 32
    unsigned* tick = (unsigned*)(esum + BB);            // 32 u32
    float* los   = (float*)(tick + BB);                 // 151 slots: 2,473,984
    float* fp    = los + (size_t)(TT + 1) * BB * RNND;  // 6,553,600
    float* G     = fp + (size_t)BB * LL * ATTD;         // 6,553,600

    // los slot 0 = lo(-1) = zeros; tick must start 0 (winners self-reset).
    hipMemsetAsync(los, 0, (size_t)BB * RNND * sizeof(float), stream);
    hipMemsetAsync(tick, 0, BB * sizeof(unsigned), stream);
    hipMemcpyAsync(h0, initstate, (size_t)BB * RNND * sizeof(float),
                   hipMemcpyDeviceToDevice, stream);

    k_proj512<<<800, 256, 0, stream>>>(features, W1, fp);
    k_proj512<<<800, 256, 0, stream>>>(features, outW + (size_t)512 * RNND, G);

    float* hin = h0;
    float* hout = h1;
    for (int t = 0; t < TT; ++t) {
        k_gates<<<120, 256, 0, stream>>>(emb, formula, gruK, gruR, hin,
                                         los + (size_t)t * BB * RNND, mxp, mhp, t);
        k_qh<<<128, 256, 0, stream>>>(mxp, mhp, gruB, W2, outW, hin, hout,
                                      qhp, gdot, esum);
        k_attn<<<BB * LS3, 256, 0, stream>>>(qhp, V, fp, G, gdot, esum, tick,
                                             los + (size_t)(t + 1) * BB * RNND);
        float* tmp = hin; hin = hout; hout = tmp;
    }
    k_final<<<75 * 40, 256, 0, stream>>>(los, projW, logits);
}

// Round 11
// 10479.255 us; speedup vs baseline: 1.5582x; 1.5582x over previous
//
#include <hip/hip_runtime.h>

#define BB 32
#define TT 150
#define LL 400
#define FEATD 512
#define RNND 512
#define ATTD 512
#define EMBD 256
#define VOCABD 5000
#define G3 1536

__device__ __forceinline__ float fsigmoid(float x) { return 1.f / (1.f + __expf(-x)); }
__device__ __forceinline__ float ftanh(float x) {
    x = fminf(15.f, fmaxf(-15.f, x));
    float e = __expf(2.f * x);
    return 1.f - 2.f / (e + 1.f);
}
__device__ __forceinline__ void fma4(float4& a, const float4 w, const float s) {
    a.x += w.x * s; a.y += w.y * s; a.z += w.z * s; a.w += w.w * s;
}

// ---------------- one-time GEMM: [B*L,512] @ [512,512] (fp and G) ----------------
__global__ void __launch_bounds__(256) k_proj512(const float* __restrict__ features,
                                                 const float* __restrict__ W,
                                                 float* __restrict__ outb) {
    __shared__ float sa[64 * 68];
    int blt = blockIdx.x >> 2, at = blockIdx.x & 3;
    int bl0 = blt * 64;
    int tid = threadIdx.x;
    int aq = tid & 31, blg = tid >> 5;
    float4 acc[8] = {};
    for (int kc = 0; kc < FEATD; kc += 64) {
        __syncthreads();
        for (int it = 0; it < 16; ++it) {
            int lin = it * 256 + tid;
            int k = lin & 63, bl = lin >> 6;
            sa[k * 68 + bl] = features[((size_t)bl0 + bl) * FEATD + kc + k];
        }
        __syncthreads();
#pragma unroll 4
        for (int k = 0; k < 64; ++k) {
            float4 w = *(const float4*)&W[(size_t)(kc + k) * 512 + at * 128 + aq * 4];
            float4 s0 = *(const float4*)&sa[k * 68 + blg * 8];
            float4 s1 = *(const float4*)&sa[k * 68 + blg * 8 + 4];
            fma4(acc[0], w, s0.x); fma4(acc[1], w, s0.y);
            fma4(acc[2], w, s0.z); fma4(acc[3], w, s0.w);
            fma4(acc[4], w, s1.x); fma4(acc[5], w, s1.y);
            fma4(acc[6], w, s1.z); fma4(acc[7], w, s1.w);
        }
    }
#pragma unroll
    for (int i = 0; i < 8; ++i)
        *(float4*)&outb[((size_t)bl0 + blg * 8 + i) * 512 + at * 128 + aq * 4] = acc[i];
}

// ---------------- K1: gate GEMM partials + inline lo(t-1). 120 blocks x 512 ----------------
// mx: [emb(tok) | lo(t-1)] (K=768) @ Wk -> mxp[3], mh: h(t-1) @ Wr -> mhp[2].
// lo(t-1) = tanh(hpart + gdot/esum) via vectorized transposed partials
// (hppT float4, gdotT 2x float4). jt==0 lo-blocks write los[t].
__global__ void __launch_bounds__(512) k_gates(
    const float* __restrict__ emb, const int* __restrict__ formula,
    const float* __restrict__ Wk, const float* __restrict__ Wr,
    const float* __restrict__ hin, const float* __restrict__ hppT,
    const float* __restrict__ gdotT, const float* __restrict__ esumT,
    float* __restrict__ mxp, float* __restrict__ mhp,
    float* __restrict__ los, int t) {
    __shared__ float sm[256 * 33];
    __shared__ float sinv[BB];
    __shared__ int stok[BB];
    int id = blockIdx.x, tid = threadIdx.x;
    bool isMX = id < 72;
    int jt, ks; const float* W; float* ob;
    if (isMX) { jt = id / 3; ks = id % 3; W = Wk; ob = mxp; }
    else { int r = id - 72; jt = r >> 1; ks = r & 1; W = Wr; ob = mhp; }
    int k0 = ks * 256;
    if (isMX && ks == 0 && tid < BB) stok[tid] = formula[tid * TT + t];
    if (isMX && ks > 0 && t > 0 && tid < BB) {
        float4 e0 = *(const float4*)&esumT[tid * 8];
        float4 e1 = *(const float4*)&esumT[tid * 8 + 4];
        sinv[tid] = 1.f / (e0.x + e0.y + e0.z + e0.w + e1.x + e1.y + e1.z + e1.w);
    }
    __syncthreads();
    for (int it = 0; it < 16; ++it) {
        int lin = it * 512 + tid;
        int k = lin & 255, b = lin >> 8;
        float v;
        if (!isMX) {
            v = hin[(size_t)b * RNND + k0 + k];
        } else if (ks == 0) {
            v = emb[(size_t)stok[b] * EMBD + k];
        } else {
            int kr = (ks - 1) * 256 + k;
            if (t == 0) {
                v = 0.f;  // lo(-1) = 0
            } else {
                float4 hp = *(const float4*)&hppT[((size_t)b * RNND + kr) * 4];
                float4 g0 = *(const float4*)&gdotT[((size_t)b * RNND + kr) * 8];
                float4 g1 = *(const float4*)&gdotT[((size_t)b * RNND + kr) * 8 + 4];
                float hps = hp.x + hp.y + hp.z + hp.w;
                float gg = g0.x + g0.y + g0.z + g0.w + g1.x + g1.y + g1.z + g1.w;
                v = ftanh(hps + sinv[b] * gg);
            }
            if (jt == 0) los[((size_t)t * BB + b) * RNND + kr] = v;  // slot t = lo(t-1)
        }
        sm[k * 33 + b] = v;
    }
    __syncthreads();
    int jq = tid & 15, b = tid >> 4;
    int j = jt * 64 + jq * 4;
    float4 acc = {0, 0, 0, 0};
#pragma unroll 4
    for (int k = 0; k < 256; ++k) {
        float4 w = *(const float4*)&W[(size_t)(k0 + k) * G3 + j];
        fma4(acc, w, sm[k * 33 + b]);
    }
    *(float4*)&ob[((size_t)ks * BB + b) * G3 + j] = acc;
}

// ---------------- K2: combine -> h(t) + q|hpart partials (transposed). 64 blocks x 512 ----------------
// blocks = tile(16) x ks(4, 128-k). Weights read exactly once per step.
__global__ void __launch_bounds__(512) k_qh(
    const float* __restrict__ mxp, const float* __restrict__ mhp,
    const float* __restrict__ gruB, const float* __restrict__ W2,
    const float* __restrict__ outW, const float* __restrict__ hin,
    float* __restrict__ hout, float* __restrict__ qpT,
    float* __restrict__ hppT) {
    __shared__ float sm[128 * 33];
    int tile = blockIdx.x >> 2, ks = blockIdx.x & 3;
    int tid = threadIdx.x;
    int k0 = ks * 128;
    for (int it = 0; it < 8; ++it) {
        int lin = it * 512 + tid;
        int k = lin & 127, b = lin >> 7;
        int j = k0 + k;
        size_t m0 = ((size_t)0 * BB + b) * G3, m1 = ((size_t)1 * BB + b) * G3,
               m2 = ((size_t)2 * BB + b) * G3;
        float xz = gruB[j] + mxp[m0 + j] + mxp[m1 + j] + mxp[m2 + j];
        float xr = gruB[512 + j] + mxp[m0 + 512 + j] + mxp[m1 + 512 + j] + mxp[m2 + 512 + j];
        float xh = gruB[1024 + j] + mxp[m0 + 1024 + j] + mxp[m1 + 1024 + j] + mxp[m2 + 1024 + j];
        float rz = gruB[G3 + j] + mhp[m0 + j] + mhp[m1 + j];
        float rr = gruB[G3 + 512 + j] + mhp[m0 + 512 + j] + mhp[m1 + 512 + j];
        float rh = gruB[G3 + 1024 + j] + mhp[m0 + 1024 + j] + mhp[m1 + 1024 + j];
        float z = fsigmoid(xz + rz), r = fsigmoid(xr + rr);
        float hh = ftanh(xh + r * rh);
        float hn = z * hin[(size_t)b * RNND + j] + (1.f - z) * hh;
        sm[k * 33 + b] = hn;
        if (tile == 0) hout[(size_t)b * RNND + j] = hn;
    }
    __syncthreads();
    const float* W = (tile < 8) ? W2 : outW;  // outW rows [0,512) = h part
    int cb = (tile & 7) * 64;
    int jq = tid & 15, b = tid >> 4;
    int j = cb + jq * 4;
    float4 acc = {0, 0, 0, 0};
#pragma unroll 4
    for (int k = 0; k < 128; ++k) {
        float4 w = *(const float4*)&W[(size_t)(k0 + k) * 512 + j];
        fma4(acc, w, sm[k * 33 + b]);
    }
    float* outp = (tile < 8) ? qpT : hppT;
    float av[4] = {acc.x, acc.y, acc.z, acc.w};
#pragma unroll
    for (int i = 0; i < 4; ++i)
        outp[((size_t)b * 512 + j + i) * 4 + ks] = av[i];
}

// ---------------- K3: scores + exp + gdot partials (transposed). 256 blocks x 512 ----------------
__global__ void __launch_bounds__(512) k_attn(
    const float* __restrict__ qpT, const float* __restrict__ V,
    const float* __restrict__ fp, const float* __restrict__ G,
    float* __restrict__ gdotT, float* __restrict__ esumT) {
    __shared__ float sq[ATTD];
    __shared__ float sV[ATTD];
    __shared__ float se[64];
    int b = blockIdx.x >> 3, ls = blockIdx.x & 7, l0 = ls * 50;
    int tid = threadIdx.x;
    {
        float4 qp = *(const float4*)&qpT[((size_t)b * 512 + tid) * 4];
        sq[tid] = qp.x + qp.y + qp.z + qp.w;
        sV[tid] = V[tid];
    }
    if (tid >= 50 && tid < 64) se[tid] = 0.f;
    __syncthreads();
    int lane = tid & 63, wv = tid >> 6;
    float4 q0 = ((const float4*)sq)[lane], q1 = ((const float4*)sq)[64 + lane];
    float4 v0 = ((const float4*)sV)[lane], v1 = ((const float4*)sV)[64 + lane];
    for (int ll = wv; ll < 50; ll += 8) {
        const float4* row = (const float4*)(fp + ((size_t)b * LL + l0 + ll) * ATTD);
        float4 f0 = row[lane], f1 = row[64 + lane];
        float d = ftanh(f0.x + q0.x) * v0.x + ftanh(f0.y + q0.y) * v0.y +
                  ftanh(f0.z + q0.z) * v0.z + ftanh(f0.w + q0.w) * v0.w +
                  ftanh(f1.x + q1.x) * v1.x + ftanh(f1.y + q1.y) * v1.y +
                  ftanh(f1.z + q1.z) * v1.z + ftanh(f1.w + q1.w) * v1.w;
#pragma unroll
        for (int o = 32; o > 0; o >>= 1) d += __shfl_xor(d, o);
        if (lane == 0) se[ll] = __expf(d);  // |score| <= sum|V| ~ 20, fp32-safe
    }
    __syncthreads();
    if (tid < 64) {
        float x = se[tid];
#pragma unroll
        for (int o = 32; o > 0; o >>= 1) x += __shfl_xor(x, o);
        if (tid == 0) esumT[b * 8 + ls] = x;
    }
    // gdot partial over this l-chunk: thread = one column
    float a = 0.f;
#pragma unroll 2
    for (int l = 0; l < 50; ++l)
        a += se[l] * G[((size_t)b * LL + l0 + l) * RNND + tid];
    gdotT[((size_t)b * RNND + tid) * 8 + ls] = a;
}

// ---------------- tail: lo(149) -> los slot 150. 32 blocks x 512 ----------------
__global__ void __launch_bounds__(512) k_lo_tail(
    const float* __restrict__ hppT, const float* __restrict__ gdotT,
    const float* __restrict__ esumT, float* __restrict__ los) {
    int b = blockIdx.x, tid = threadIdx.x;
    float4 e0 = *(const float4*)&esumT[b * 8];
    float4 e1 = *(const float4*)&esumT[b * 8 + 4];
    float inv = 1.f / (e0.x + e0.y + e0.z + e0.w + e1.x + e1.y + e1.z + e1.w);
    float4 hp = *(const float4*)&hppT[((size_t)b * RNND + tid) * 4];
    float4 g0 = *(const float4*)&gdotT[((size_t)b * RNND + tid) * 8];
    float4 g1 = *(const float4*)&gdotT[((size_t)b * RNND + tid) * 8 + 4];
    float hps = hp.x + hp.y + hp.z + hp.w;
    float gg = g0.x + g0.y + g0.z + g0.w + g1.x + g1.y + g1.z + g1.w;
    los[((size_t)TT * BB + b) * RNND + tid] = ftanh(hps + inv * gg);
}

// ---------------- final: logits = los[1..150] @ projW ----------------
__global__ void __launch_bounds__(256) k_final(
    const float* __restrict__ los, const float* __restrict__ Wp,
    float* __restrict__ out) {
    __shared__ float sa[64 * 68];
    __shared__ unsigned srow[64];
    int mt = blockIdx.x / 40, vt = blockIdx.x % 40;
    int r0 = mt * 64;
    int tid = threadIdx.x;
    if (tid < 64) {
        int r = r0 + tid;
        int bb = r / TT, t = r % TT;
        srow[tid] = (unsigned)(((size_t)(t + 1) * BB + bb) * RNND);
    }
    int aq = tid & 31, blg = tid >> 5;
    int v = vt * 128 + aq * 4;
    bool vok = v < VOCABD;
    float4 acc[8] = {};
    __syncthreads();
    for (int kc = 0; kc < RNND; kc += 64) {
        for (int it = 0; it < 16; ++it) {
            int lin = it * 256 + tid;
            int k = lin & 63, rl = lin >> 6;
            sa[k * 68 + rl] = los[srow[rl] + kc + k];
        }
        __syncthreads();
        if (vok) {
#pragma unroll 4
            for (int k = 0; k < 64; ++k) {
                float4 w = *(const float4*)&Wp[(size_t)(kc + k) * VOCABD + v];
                float4 s0 = *(const float4*)&sa[k * 68 + blg * 8];
                float4 s1 = *(const float4*)&sa[k * 68 + blg * 8 + 4];
                fma4(acc[0], w, s0.x); fma4(acc[1], w, s0.y);
                fma4(acc[2], w, s0.z); fma4(acc[3], w, s0.w);
                fma4(acc[4], w, s1.x); fma4(acc[5], w, s1.y);
                fma4(acc[6], w, s1.z); fma4(acc[7], w, s1.w);
            }
        }
        __syncthreads();
    }
    if (vok) {
#pragma unroll
        for (int i = 0; i < 8; ++i)
            *(float4*)&out[(size_t)(r0 + blg * 8 + i) * VOCABD + v] = acc[i];
    }
}

extern "C" void kernel_launch(void* const* d_in, const int* in_sizes, int n_in,
                              void* d_out, int out_size, void* d_ws, size_t ws_size,
                              hipStream_t stream) {
    const float* features  = (const float*)d_in[0];
    const float* initstate = (const float*)d_in[1];
    const float* emb       = (const float*)d_in[2];
    const float* gruK      = (const float*)d_in[3];
    const float* gruR      = (const float*)d_in[4];
    const float* gruB      = (const float*)d_in[5];
    const float* W1        = (const float*)d_in[6];
    const float* W2        = (const float*)d_in[7];
    const float* V         = (const float*)d_in[8];
    const float* outW      = (const float*)d_in[9];
    const float* projW     = (const float*)d_in[10];
    const int*   formula   = (const int*)d_in[11];
    float* logits = (float*)d_out;

    float* ws = (float*)d_ws;
    float* h0    = ws;                                  // 16,384
    float* h1    = h0 + (size_t)BB * RNND;              // 16,384
    float* mxp   = h1 + (size_t)BB * RNND;              // 147,456
    float* mhp   = mxp + (size_t)3 * BB * G3;           // 98,304
    float* qpT   = mhp + (size_t)2 * BB * G3;           // 65,536
    float* hppT  = qpT + (size_t)BB * 512 * 4;          // 65,536
    float* gdotT = hppT + (size_t)BB * 512 * 4;         // 131,072
    float* esumT = gdotT + (size_t)BB * RNND * 8;       // 256
    float* los   = esumT + BB * 8;                      // 151 slots: 2,473,984
    float* fp    = los + (size_t)(TT + 1) * BB * RNND;  // 6,553,600
    float* G     = fp + (size_t)BB * LL * ATTD;         // 6,553,600

    // los slot 0 = lo(-1) = zeros; re-zeroed every call (deterministic).
    hipMemsetAsync(los, 0, (size_t)BB * RNND * sizeof(float), stream);
    hipMemcpyAsync(h0, initstate, (size_t)BB * RNND * sizeof(float),
                   hipMemcpyDeviceToDevice, stream);

    k_proj512<<<800, 256, 0, stream>>>(features, W1, fp);
    k_proj512<<<800, 256, 0, stream>>>(features, outW + (size_t)512 * RNND, G);

    float* hin = h0;
    float* hout = h1;
    for (int t = 0; t < TT; ++t) {
        k_gates<<<120, 512, 0, stream>>>(emb, formula, gruK, gruR, hin,
                                         hppT, gdotT, esumT, mxp, mhp, los, t);
        k_qh<<<64, 512, 0, stream>>>(mxp, mhp, gruB, W2, outW, hin, hout,
                                     qpT, hppT);
        k_attn<<<256, 512, 0, stream>>>(qpT, V, fp, G, gdotT, esumT);
        float* tmp = hin; hin = hout; hout = tmp;
    }
    k_lo_tail<<<BB, 512, 0, stream>>>(hppT, gdotT, esumT, los);
    k_final<<<75 * 40, 256, 0, stream>>>(los, projW, logits);
}